// Round 1
// baseline (571.813 us; speedup 1.0000x reference)
//
#include <hip/hip_runtime.h>
#include <hip/hip_bf16.h>

#define DD 1024
#define RR 16
#define MM 512
#define KK 8
#define BB 8
#define SCALE_F 0.0625f

#define TT 4            // rows per wave-tile
#define BT 16           // rows per block-tile (4 waves * TT)
#define TILES 4         // tiles per block -> 64 rows per block

// ---------- reduce-scatter butterfly: lane l ends with sum over lanes of v[l] ----------
template <int HALF>
__device__ __forceinline__ void reduce_step(float (&v)[64], int lane) {
    const bool hi = (lane & HALF) != 0;
#pragma unroll
    for (int i = 0; i < HALF; ++i) {
        const float keep = hi ? v[i + HALF] : v[i];
        const float send = hi ? v[i] : v[i + HALF];
        v[i] = keep + __shfl_xor(send, HALF, 64);
    }
}

// ================= Kernel 1: down[row][r] = sum_d z[row][d] * A[e][d][r] =================
__global__ __launch_bounds__(256, 2)
void lora_down(const float* __restrict__ z, const float* __restrict__ A_all,
               const int* __restrict__ eidx, float* __restrict__ down)
{
    __shared__ float At[RR][DD];   // 64 KB, A transposed: At[r][d]

    const int mc = blockIdx.x;     // 0..7
    const int b  = blockIdx.y;     // 0..7
    const int k  = blockIdx.z;     // 0..7
    const int e  = eidx[k];

    const float* __restrict__ Ae = A_all + (size_t)e * (DD * RR);

    // stage A transposed (coalesced float4 reads; scattered b32 LDS writes, ~4-way = cheap, once)
    for (int f4 = threadIdx.x; f4 < DD * RR / 4; f4 += 256) {
        const int f = f4 << 2;                 // f = d*16 + r, r % 4 == 0
        const float4 v = *reinterpret_cast<const float4*>(Ae + f);
        const int d = f >> 4, r = f & 15;
        At[r + 0][d] = v.x;
        At[r + 1][d] = v.y;
        At[r + 2][d] = v.z;
        At[r + 3][d] = v.w;
    }
    __syncthreads();

    const int wave = threadIdx.x >> 6;
    const int lane = threadIdx.x & 63;
    const size_t rowbk = ((size_t)b * KK + k) * MM;
    const int mbase = mc * (BT * TILES) + wave * TT;    // row of t=0 at it=0

    const float* __restrict__ zlane = z + (rowbk + mbase) * DD + lane * 4;

    float4 bufA[TT][4], bufB[TT][4];   // z tile double buffer: [t][s] float4

    auto load_tile = [&](float4 (&buf)[TT][4], int it) {
#pragma unroll
        for (int t = 0; t < TT; ++t) {
            const float* p = zlane + (size_t)(it * BT + t) * DD;
#pragma unroll
            for (int s = 0; s < 4; ++s)
                buf[t][s] = *reinterpret_cast<const float4*>(p + s * 256);
        }
    };

    auto compute_store = [&](const float4 (&buf)[TT][4], int it) {
        float v[64];
#pragma unroll
        for (int i = 0; i < 64; ++i) v[i] = 0.f;
#pragma unroll
        for (int s = 0; s < 4; ++s) {
            const int dbase = s * 256 + lane * 4;
#pragma unroll
            for (int r = 0; r < RR; ++r) {
                const float4 a = *reinterpret_cast<const float4*>(&At[r][dbase]);
#pragma unroll
                for (int t = 0; t < TT; ++t) {
                    const float4 zv = buf[t][s];
                    float acc = v[t * 16 + r];
                    acc = fmaf(zv.x, a.x, acc);
                    acc = fmaf(zv.y, a.y, acc);
                    acc = fmaf(zv.z, a.z, acc);
                    acc = fmaf(zv.w, a.w, acc);
                    v[t * 16 + r] = acc;
                }
            }
        }
        // 63-shfl reduce-scatter: lane l <- total of v[l]; l = t*16 + r
        reduce_step<32>(v, lane);
        reduce_step<16>(v, lane);
        reduce_step<8>(v, lane);
        reduce_step<4>(v, lane);
        reduce_step<2>(v, lane);
        reduce_step<1>(v, lane);
        down[(rowbk + mbase + it * BT) * RR + lane] = v[0];   // 64 consecutive floats
    };

    load_tile(bufA, 0);
#pragma unroll
    for (int ip = 0; ip < 2; ++ip) {
        load_tile(bufB, 2 * ip + 1);
        compute_store(bufA, 2 * ip);
        if (ip == 0) load_tile(bufA, 2);
        compute_store(bufB, 2 * ip + 1);
    }
}

// ================= Kernel 2: out[row][d] = SCALE * sum_r down[row][r] * B[e][r][d] =================
__global__ __launch_bounds__(256, 2)
void lora_up(const float* __restrict__ down, const float* __restrict__ B_all,
             const int* __restrict__ eidx, float* __restrict__ out)
{
    __shared__ float Bl[RR][DD];   // 64 KB, as-is: Bl[r][d]

    const int mc = blockIdx.x;
    const int b  = blockIdx.y;
    const int k  = blockIdx.z;
    const int e  = eidx[k];

    const float* __restrict__ Be = B_all + (size_t)e * (RR * DD);
    for (int f4 = threadIdx.x; f4 < RR * DD / 4; f4 += 256)
        *reinterpret_cast<float4*>(&Bl[0][0] + (f4 << 2)) =
            *reinterpret_cast<const float4*>(Be + (f4 << 2));
    __syncthreads();

    const int wave = threadIdx.x >> 6;
    const int lane = threadIdx.x & 63;
    const size_t rowbk = ((size_t)b * KK + k) * MM;
    const int mbase = mc * (BT * TILES) + wave * TT;

    float cA[64], cB[64];   // coefficients: c[t*16 + r], wave-uniform

    auto load_c = [&](float (&c)[64], int it) {
        const float4* dp = reinterpret_cast<const float4*>(down + (rowbk + mbase + it * BT) * RR);
#pragma unroll
        for (int i = 0; i < 16; ++i) {
            const float4 v = dp[i];           // broadcast load (all lanes same addr)
            c[i * 4 + 0] = v.x;
            c[i * 4 + 1] = v.y;
            c[i * 4 + 2] = v.z;
            c[i * 4 + 3] = v.w;
        }
    };

    auto compute_store = [&](const float (&c)[64], int it) {
#pragma unroll
        for (int s = 0; s < 4; ++s) {
            const int dbase = s * 256 + lane * 4;
            float4 o[TT];
#pragma unroll
            for (int t = 0; t < TT; ++t) o[t] = make_float4(0.f, 0.f, 0.f, 0.f);
#pragma unroll
            for (int r = 0; r < RR; ++r) {
                const float4 bv = *reinterpret_cast<const float4*>(&Bl[r][dbase]);
#pragma unroll
                for (int t = 0; t < TT; ++t) {
                    const float cf = c[t * 16 + r];
                    o[t].x = fmaf(cf, bv.x, o[t].x);
                    o[t].y = fmaf(cf, bv.y, o[t].y);
                    o[t].z = fmaf(cf, bv.z, o[t].z);
                    o[t].w = fmaf(cf, bv.w, o[t].w);
                }
            }
#pragma unroll
            for (int t = 0; t < TT; ++t) {
                float4 res;
                res.x = o[t].x * SCALE_F;
                res.y = o[t].y * SCALE_F;
                res.z = o[t].z * SCALE_F;
                res.w = o[t].w * SCALE_F;
                *reinterpret_cast<float4*>(out + (rowbk + mbase + it * BT + t) * DD + dbase) = res;
            }
        }
    };

    load_c(cA, 0);
#pragma unroll
    for (int ip = 0; ip < 2; ++ip) {
        load_c(cB, 2 * ip + 1);
        compute_store(cA, 2 * ip);
        if (ip == 0) load_c(cA, 2);
        compute_store(cB, 2 * ip + 1);
    }
}

extern "C" void kernel_launch(void* const* d_in, const int* in_sizes, int n_in,
                              void* d_out, int out_size, void* d_ws, size_t ws_size,
                              hipStream_t stream) {
    const float* z     = (const float*)d_in[0];
    const float* A_all = (const float*)d_in[1];
    const float* B_all = (const float*)d_in[2];
    const int*   eidx  = (const int*)d_in[3];
    float* out  = (float*)d_out;
    float* down = (float*)d_ws;     // [B*K*M][R] fp32 = 2 MB scratch

    dim3 grid(MM / (BT * TILES), BB, KK);   // (8, 8, 8) = 512 blocks, 2/CU
    dim3 block(256);

    lora_down<<<grid, block, 0, stream>>>(z, A_all, eidx, down);
    lora_up<<<grid, block, 0, stream>>>(down, B_all, eidx, out);
}

// Round 2
// 511.968 us; speedup vs baseline: 1.1169x; 1.1169x over previous
//
#include <hip/hip_runtime.h>
#include <hip/hip_bf16.h>

#define DD 1024
#define RR 16
#define MM 512
#define KK 8
#define BB 8
#define SCALE_F 0.0625f

#define TT 2            // rows per wave-tile  (accumulator = 32 regs, buffers = 2*32 regs)
#define BT 8            // rows per block-tile (4 waves * TT)
#define TILES 8         // block covers 64 rows

// ---- reduce-scatter fold: consume current LSB of value-index against lane bit XOR ----
// After fold<32,1>,<16,2>,<8,4>,<4,8>,<2,16>: lane l holds sum over its 32-lane half of
// value j = l&31; one final xor32 add completes the 64-lane sum.
template <int LEN, int XOR>
__device__ __forceinline__ void fold(float (&v)[32], int lane) {
    const bool hi = (lane & XOR) != 0;
#pragma unroll
    for (int i = 0; i < LEN / 2; ++i) {
        const float keep = hi ? v[2 * i + 1] : v[2 * i];
        const float send = hi ? v[2 * i] : v[2 * i + 1];
        v[i] = keep + __shfl_xor(send, XOR, 64);
    }
}

// ================= Kernel 1: down[row][r] = sum_d z[row][d] * A[e][d][r] =================
__global__ __launch_bounds__(256, 2)
void lora_down(const float* __restrict__ z, const float* __restrict__ A_all,
               const int* __restrict__ eidx, float* __restrict__ down)
{
    __shared__ float At[RR][DD];   // 64 KB, A transposed: At[r][d]

    const int mc = blockIdx.x;     // 0..7
    const int b  = blockIdx.y;     // 0..7
    const int k  = blockIdx.z;     // 0..7
    const int e  = eidx[k];

    const float* __restrict__ Ae = A_all + (size_t)e * (DD * RR);

    // stage A transposed (coalesced float4 global reads; scattered b32 LDS writes, once)
    for (int f4 = threadIdx.x; f4 < DD * RR / 4; f4 += 256) {
        const int f = f4 << 2;                 // f = d*16 + r, r % 4 == 0
        const float4 v = *reinterpret_cast<const float4*>(Ae + f);
        const int d = f >> 4, r = f & 15;
        At[r + 0][d] = v.x;
        At[r + 1][d] = v.y;
        At[r + 2][d] = v.z;
        At[r + 3][d] = v.w;
    }
    __syncthreads();

    const int wave = threadIdx.x >> 6;
    const int lane = threadIdx.x & 63;
    const size_t rowbk = ((size_t)b * KK + k) * MM;
    const int mbase = mc * 64 + wave * TT;              // row of t=0 at it=0
    const float* __restrict__ zlane = z + (rowbk + mbase) * DD + lane * 4;

    float4 bufA[TT][4], bufB[TT][4];   // z tile double buffer (16 float4 = 64 VGPRs)

    auto load_tile = [&](float4 (&buf)[TT][4], int it) {
#pragma unroll
        for (int t = 0; t < TT; ++t) {
            const float* p = zlane + (size_t)(it * BT + t) * DD;
#pragma unroll
            for (int s = 0; s < 4; ++s)
                buf[t][s] = *reinterpret_cast<const float4*>(p + s * 256);
        }
    };

    auto compute_store = [&](const float4 (&buf)[TT][4], int it) {
        float v[32];
#pragma unroll
        for (int i = 0; i < 32; ++i) v[i] = 0.f;
#pragma unroll
        for (int s = 0; s < 4; ++s) {
            const int dbase = s * 256 + lane * 4;
#pragma unroll
            for (int r = 0; r < RR; ++r) {
                const float4 a = *reinterpret_cast<const float4*>(&At[r][dbase]);
#pragma unroll
                for (int t = 0; t < TT; ++t) {
                    const float4 zv = buf[t][s];
                    float acc = v[t * 16 + r];
                    acc = fmaf(zv.x, a.x, acc);
                    acc = fmaf(zv.y, a.y, acc);
                    acc = fmaf(zv.z, a.z, acc);
                    acc = fmaf(zv.w, a.w, acc);
                    v[t * 16 + r] = acc;
                }
            }
        }
        // small-stride-first reduce-scatter: 30 DPP-able shuffles + 2 wide ones
        fold<32, 1>(v, lane);
        fold<16, 2>(v, lane);
        fold<8, 4>(v, lane);
        fold<4, 8>(v, lane);
        fold<2, 16>(v, lane);
        const float total = v[0] + __shfl_xor(v[0], 32, 64);
        if (lane < 32)   // j = t*16+r = lane; 32 consecutive floats
            down[(rowbk + mbase + it * BT) * RR + lane] = total;
    };

    load_tile(bufA, 0);
#pragma unroll 1
    for (int ip = 0; ip < TILES / 2; ++ip) {
        load_tile(bufB, 2 * ip + 1);
        compute_store(bufA, 2 * ip);
        if (ip < TILES / 2 - 1) load_tile(bufA, 2 * ip + 2);
        compute_store(bufB, 2 * ip + 1);
    }
}

// ================= Kernel 2: out[row][d] = SCALE * sum_r down[row][r] * B[e][r][d] =================
__global__ __launch_bounds__(256, 2)
void lora_up(const float* __restrict__ down, const float* __restrict__ B_all,
             const int* __restrict__ eidx, float* __restrict__ out)
{
    __shared__ float Bl[RR][DD];   // 64 KB, as-is: Bl[r][d]

    const int mc = blockIdx.x;
    const int b  = blockIdx.y;
    const int k  = blockIdx.z;
    const int e  = eidx[k];

    const float* __restrict__ Be = B_all + (size_t)e * (RR * DD);
    for (int f4 = threadIdx.x; f4 < RR * DD / 4; f4 += 256)
        *reinterpret_cast<float4*>(&Bl[0][0] + (f4 << 2)) =
            *reinterpret_cast<const float4*>(Be + (f4 << 2));
    __syncthreads();

    const int wave = threadIdx.x >> 6;
    const int lane = threadIdx.x & 63;
    const size_t rowbk = ((size_t)b * KK + k) * MM;
    const int mbase = mc * 64 + wave * TT;

    float cA[32], cB[32];   // coefficients c[t*16 + r], wave-uniform (32+32 regs)

    auto load_c = [&](float (&c)[32], int it) {
        const float4* dp = reinterpret_cast<const float4*>(down + (rowbk + mbase + it * BT) * RR);
#pragma unroll
        for (int i = 0; i < 8; ++i) {
            const float4 v = dp[i];           // broadcast load (all lanes same addr)
            c[i * 4 + 0] = v.x;
            c[i * 4 + 1] = v.y;
            c[i * 4 + 2] = v.z;
            c[i * 4 + 3] = v.w;
        }
    };

    auto compute_store = [&](const float (&c)[32], int it) {
#pragma unroll
        for (int s = 0; s < 4; ++s) {
            const int dbase = s * 256 + lane * 4;
            float4 o[TT];
#pragma unroll
            for (int t = 0; t < TT; ++t) o[t] = make_float4(0.f, 0.f, 0.f, 0.f);
#pragma unroll
            for (int r = 0; r < RR; ++r) {
                const float4 bv = *reinterpret_cast<const float4*>(&Bl[r][dbase]);
#pragma unroll
                for (int t = 0; t < TT; ++t) {
                    const float cf = c[t * 16 + r];
                    o[t].x = fmaf(cf, bv.x, o[t].x);
                    o[t].y = fmaf(cf, bv.y, o[t].y);
                    o[t].z = fmaf(cf, bv.z, o[t].z);
                    o[t].w = fmaf(cf, bv.w, o[t].w);
                }
            }
#pragma unroll
            for (int t = 0; t < TT; ++t) {
                float4 res;
                res.x = o[t].x * SCALE_F;
                res.y = o[t].y * SCALE_F;
                res.z = o[t].z * SCALE_F;
                res.w = o[t].w * SCALE_F;
                *reinterpret_cast<float4*>(out + (rowbk + mbase + it * BT + t) * DD + dbase) = res;
            }
        }
    };

    load_c(cA, 0);
#pragma unroll 1
    for (int ip = 0; ip < TILES / 2; ++ip) {
        load_c(cB, 2 * ip + 1);
        compute_store(cA, 2 * ip);
        if (ip < TILES / 2 - 1) load_c(cA, 2 * ip + 2);
        compute_store(cB, 2 * ip + 1);
    }
}

extern "C" void kernel_launch(void* const* d_in, const int* in_sizes, int n_in,
                              void* d_out, int out_size, void* d_ws, size_t ws_size,
                              hipStream_t stream) {
    const float* z     = (const float*)d_in[0];
    const float* A_all = (const float*)d_in[1];
    const float* B_all = (const float*)d_in[2];
    const int*   eidx  = (const int*)d_in[3];
    float* out  = (float*)d_out;
    float* down = (float*)d_ws;     // [B*K*M][R] fp32 = 2 MB scratch

    dim3 grid(MM / 64, BB, KK);     // (8, 8, 8) = 512 blocks, 2/CU
    dim3 block(256);

    lora_down<<<grid, block, 0, stream>>>(z, A_all, eidx, down);
    lora_up<<<grid, block, 0, stream>>>(down, B_all, eidx, out);
}